// Round 8
// baseline (114.718 us; speedup 1.0000x reference)
//
#include <hip/hip_runtime.h>
#include <hip/hip_bf16.h>

#define NN 8192
#define FF 128
#define BM 64
#define BK 64
#define KS 8
#define KCH (NN / KS)      // 1024 K per block
#define NSTEP (KCH / BK)   // 16

typedef __attribute__((ext_vector_type(8))) short bf16x8;   // 8 bf16 (4 VGPR)
typedef __attribute__((ext_vector_type(4))) float f32x4;

__device__ __forceinline__ short f2bf(float f) {
  unsigned u = __float_as_uint(f);
  u += 0x7FFFu + ((u >> 16) & 1u);
  return (short)(u >> 16);
}
__device__ __forceinline__ float bf2f(short s) {
  return __uint_as_float(((unsigned)(unsigned short)s) << 16);
}

// raw barrier: ds-ops drained (lgkmcnt(0)) but global loads stay in flight.
#define BAR() do {                                              \
    asm volatile("s_waitcnt lgkmcnt(0)" ::: "memory");          \
    __builtin_amdgcn_s_barrier();                               \
  } while (0)

// ---- kernel 1: deg[i] = rowsum(adj)+1 ; dinv[i] = (deg+1e-8)^-0.5 ----
__global__ __launch_bounds__(256) void k_deg(const float* __restrict__ adj,
                                             float* __restrict__ dinv) {
  const int row = blockIdx.x;
  const float4* p = (const float4*)(adj + (size_t)row * NN);
  float s = 0.f;
#pragma unroll
  for (int it = 0; it < 8; ++it) {
    float4 v = p[it * 256 + threadIdx.x];
    s += (v.x + v.y) + (v.z + v.w);
  }
#pragma unroll
  for (int off = 32; off > 0; off >>= 1) s += __shfl_down(s, off, 64);
  __shared__ float partial[4];
  if ((threadIdx.x & 63) == 0) partial[threadIdx.x >> 6] = s;
  __syncthreads();
  if (threadIdx.x == 0) {
    float deg = (partial[0] + partial[1]) + (partial[2] + partial[3]) + 1.0f;
    dinv[row] = 1.0f / sqrtf(deg + 1e-8f);
  }
}

// ---- kernel 2: yT[f][i] = dinv[i] * x[i][f]  (bf16, transposed for NT GEMM) ----
__global__ __launch_bounds__(256) void k_scale_t(const float* __restrict__ x,
                                                 const float* __restrict__ dinv,
                                                 short* __restrict__ yT) {
  __shared__ float tile[64][129];
  const int r0 = blockIdx.x * 64;
  const int tid = threadIdx.x;
#pragma unroll
  for (int it = 0; it < 8; ++it) {
    int q = it * 256 + tid;
    int r = q >> 5;
    int c = q & 31;
    float4 v = ((const float4*)(x + (size_t)(r0 + r) * FF))[c];
    float d = dinv[r0 + r];
    tile[r][c * 4 + 0] = v.x * d;
    tile[r][c * 4 + 1] = v.y * d;
    tile[r][c * 4 + 2] = v.z * d;
    tile[r][c * 4 + 3] = v.w * d;
  }
  __syncthreads();
  const int f = tid >> 1;
  const int i0 = (tid & 1) * 32;
#pragma unroll
  for (int g = 0; g < 4; ++g) {
    bf16x8 o;
#pragma unroll
    for (int j = 0; j < 8; ++j) o[j] = f2bf(tile[i0 + g * 8 + j][f]);
    *(bf16x8*)(yT + (size_t)f * NN + r0 + i0 + g * 8) = o;
  }
}

// ---- kernel 3: zpart[ks] = adj[:, ksliced] @ y. K-split MFMA GEMM. ----
// 1024 blocks (128 M-tiles x 8 K-slices), 512 thr = 8 waves (2M x 4N),
// BM=64, BN=128(all), BK=64, LDS double-buffer. FOUR register staging sets:
// loads for tile t+4 issue at phase t, staged at phase t+3 -> ~3 phases
// (>HBM latency) of cover; one lgkmcnt-only barrier per phase.
__global__ __launch_bounds__(512, 4) void k_gemm(const float* __restrict__ adj,
                                                 const short* __restrict__ yT,
                                                 short* __restrict__ zpart) {
  __shared__ short As[2][BM][72];     // bf16, +8 pad
  __shared__ short Bs[2][128][72];
  const int tid = threadIdx.x;
  const int wave = tid >> 6;
  const int lane = tid & 63;
  const int mb = 127 - (int)(blockIdx.x & 127);   // reverse: read L3-warm rows first
  const int ks = blockIdx.x >> 7;
  const int row0 = mb * BM;
  const size_t kbase = (size_t)ks * KCH;

  // staging maps: A = 64 rows x 64 f32 (8 f32/thread); B = 128 rows x 64 bf16
  const int s_ar = tid >> 3;
  const int s_ac = (tid & 7) * 8;
  const float* pa  = adj + (size_t)(row0 + s_ar) * NN + kbase + s_ac;
  const short* pb0 = yT + (size_t)s_ar * NN + kbase + s_ac;
  const short* pb1 = yT + (size_t)(s_ar + 64) * NN + kbase + s_ac;

  const int wm = (wave >> 2) * 32;   // 0/32
  const int wn = (wave & 3) * 32;    // 0/32/64/96
  const int fr = lane & 15;
  const int kh = (lane >> 4) * 8;

  f32x4 acc00 = {0.f,0.f,0.f,0.f}, acc01 = acc00, acc10 = acc00, acc11 = acc00;

  // 4 named staging sets (static indexing only — rule #20)
  float4 a0lo, a0hi, a1lo, a1hi, a2lo, a2hi, a3lo, a3hi;
  bf16x8 b00, b01, b10, b11, b20, b21, b30, b31;

#define LOADT(alo, ahi, b0v, b1v, koff) do {                                   \
    alo = *(const float4*)(pa + (koff));                                       \
    ahi = *(const float4*)(pa + (koff) + 4);                                   \
    b0v = *(const bf16x8*)(pb0 + (koff));                                      \
    b1v = *(const bf16x8*)(pb1 + (koff));                                      \
  } while (0)

#define STAGE(BUF, alo, ahi, b0v, b1v) do {                                    \
    bf16x8 ap_;                                                                \
    ap_[0] = f2bf(alo.x); ap_[1] = f2bf(alo.y);                                \
    ap_[2] = f2bf(alo.z); ap_[3] = f2bf(alo.w);                                \
    ap_[4] = f2bf(ahi.x); ap_[5] = f2bf(ahi.y);                                \
    ap_[6] = f2bf(ahi.z); ap_[7] = f2bf(ahi.w);                                \
    *(bf16x8*)&As[BUF][s_ar][s_ac] = ap_;                                      \
    *(bf16x8*)&Bs[BUF][s_ar][s_ac] = b0v;                                      \
    *(bf16x8*)&Bs[BUF][s_ar + 64][s_ac] = b1v;                                 \
  } while (0)

#define COMPUTE(BUF) do {                                                      \
    _Pragma("unroll")                                                          \
    for (int kk = 0; kk < 2; ++kk) {                                           \
      bf16x8 a0 = *(const bf16x8*)&As[BUF][wm + fr][kk * 32 + kh];             \
      bf16x8 a1 = *(const bf16x8*)&As[BUF][wm + 16 + fr][kk * 32 + kh];        \
      bf16x8 b0 = *(const bf16x8*)&Bs[BUF][wn + fr][kk * 32 + kh];             \
      bf16x8 b1 = *(const bf16x8*)&Bs[BUF][wn + 16 + fr][kk * 32 + kh];        \
      acc00 = __builtin_amdgcn_mfma_f32_16x16x32_bf16(a0, b0, acc00, 0, 0, 0); \
      acc01 = __builtin_amdgcn_mfma_f32_16x16x32_bf16(a0, b1, acc01, 0, 0, 0); \
      acc10 = __builtin_amdgcn_mfma_f32_16x16x32_bf16(a1, b0, acc10, 0, 0, 0); \
      acc11 = __builtin_amdgcn_mfma_f32_16x16x32_bf16(a1, b1, acc11, 0, 0, 0); \
    }                                                                          \
  } while (0)

  // prologue: tiles 0..3 -> S0..S3; tile0 staged to LDS0
  LOADT(a0lo, a0hi, b00, b01, 0);
  LOADT(a1lo, a1hi, b10, b11, BK);
  LOADT(a2lo, a2hi, b20, b21, 2 * BK);
  LOADT(a3lo, a3hi, b30, b31, 3 * BK);
  STAGE(0, a0lo, a0hi, b00, b01);   // counted vmcnt: waits only S0's loads
  BAR();

  for (int t0 = 0; t0 < NSTEP; t0 += 4) {
    // phase t0+0: LDS0 holds tile t0; S0 free -> load tile t0+4
    if (t0 + 4 < NSTEP) LOADT(a0lo, a0hi, b00, b01, (t0 + 4) * BK);
    COMPUTE(0);
    STAGE(1, a1lo, a1hi, b10, b11);               // tile t0+1 (loaded 3+ phases ago)
    BAR();
    // phase t0+1
    if (t0 + 5 < NSTEP) LOADT(a1lo, a1hi, b10, b11, (t0 + 5) * BK);
    COMPUTE(1);
    STAGE(0, a2lo, a2hi, b20, b21);               // tile t0+2
    BAR();
    // phase t0+2
    if (t0 + 6 < NSTEP) LOADT(a2lo, a2hi, b20, b21, (t0 + 6) * BK);
    COMPUTE(0);
    STAGE(1, a3lo, a3hi, b30, b31);               // tile t0+3
    BAR();
    // phase t0+3
    if (t0 + 7 < NSTEP) LOADT(a3lo, a3hi, b30, b31, (t0 + 7) * BK);
    COMPUTE(1);
    if (t0 + 4 < NSTEP) STAGE(0, a0lo, a0hi, b00, b01);   // tile t0+4
    BAR();
  }

  // epilogue: D layout col=lane&15, row=(lane>>4)*4+r ; store bf16 partials
  const int r4 = (lane >> 4) * 4;
  short* zp = zpart + ((size_t)ks << 20);   // slice stride 8192*128
#pragma unroll
  for (int r = 0; r < 4; ++r) {
    int gi0 = row0 + wm + r4 + r;
    int gi1 = gi0 + 16;
    zp[(size_t)gi0 * FF + wn + fr]      = f2bf(acc00[r]);
    zp[(size_t)gi0 * FF + wn + 16 + fr] = f2bf(acc01[r]);
    zp[(size_t)gi1 * FF + wn + fr]      = f2bf(acc10[r]);
    zp[(size_t)gi1 * FF + wn + 16 + fr] = f2bf(acc11[r]);
  }
#undef LOADT
#undef STAGE
#undef COMPUTE
}

// ---- kernel 4: out = relu((dinv*(sum_ks zpart + dinv*x)) @ W) ----
__global__ __launch_bounds__(256) void k_out(const short* __restrict__ zpart,
                                             const float* __restrict__ x,
                                             const float* __restrict__ dinv,
                                             const float* __restrict__ w,
                                             float* __restrict__ out) {
  __shared__ float zs[16][128];
  const int r0 = blockIdx.x * 16;
  const int tid = threadIdx.x;
#pragma unroll
  for (int half = 0; half < 2; ++half) {
    int p = half * 256 + tid;
    int r = p >> 5;
    int c4 = p & 31;
    int gi = r0 + r;
    const short* base = zpart + (size_t)gi * FF + c4 * 4;
    float s0 = 0.f, s1 = 0.f, s2 = 0.f, s3 = 0.f;
#pragma unroll
    for (int sidx = 0; sidx < KS; ++sidx) {
      short4 v = *(const short4*)(base + ((size_t)sidx << 20));
      s0 += bf2f(v.x); s1 += bf2f(v.y); s2 += bf2f(v.z); s3 += bf2f(v.w);
    }
    float4 xv = *(const float4*)(x + (size_t)gi * FF + c4 * 4);
    float di = dinv[gi];
    float di2 = di * di;
    zs[r][c4 * 4 + 0] = di * s0 + di2 * xv.x;
    zs[r][c4 * 4 + 1] = di * s1 + di2 * xv.y;
    zs[r][c4 * 4 + 2] = di * s2 + di2 * xv.z;
    zs[r][c4 * 4 + 3] = di * s3 + di2 * xv.w;
  }
  __syncthreads();
  const int f = tid & 127;
  const int rg = (tid >> 7) * 8;
  float acc[8] = {0.f, 0.f, 0.f, 0.f, 0.f, 0.f, 0.f, 0.f};
#pragma unroll 4
  for (int k = 0; k < 128; ++k) {
    float wv = w[k * FF + f];
#pragma unroll
    for (int r = 0; r < 8; ++r) acc[r] += zs[rg + r][k] * wv;
  }
#pragma unroll
  for (int r = 0; r < 8; ++r) {
    out[(size_t)(r0 + rg + r) * FF + f] = fmaxf(acc[r], 0.0f);
  }
}

extern "C" void kernel_launch(void* const* d_in, const int* in_sizes, int n_in,
                              void* d_out, int out_size, void* d_ws, size_t ws_size,
                              hipStream_t stream) {
  const float* x   = (const float*)d_in[0];
  const float* adj = (const float*)d_in[1];
  const float* w   = (const float*)d_in[2];
  float* out = (float*)d_out;

  float* dinv  = (float*)d_ws;                                  // 32 KiB @ 0
  short* yT    = (short*)((char*)d_ws + 64 * 1024);             // 2 MiB bf16 [128][8192]
  short* zpart = (short*)((char*)d_ws + 4 * 1024 * 1024);       // 16 MiB bf16 [8][8192][128]

  k_deg    <<<NN,      256, 0, stream>>>(adj, dinv);
  k_scale_t<<<NN / 64, 256, 0, stream>>>(x, dinv, yT);
  k_gemm   <<<128 * KS, 512, 0, stream>>>(adj, yT, zpart);
  k_out    <<<NN / 16, 256, 0, stream>>>(zpart, x, dinv, w, out);
}